// Round 15
// baseline (4252.490 us; speedup 1.0000x reference)
//
#include <hip/hip_runtime.h>
#include <stdint.h>

#define SEQ   16384
#define EMB   50
#define HID   300
#define G4    1200
#define NTAG  20
#define START 18
#define STOPT 19
#define NEGV  -10000.0f
#define NC    64    // viterbi chunks (r8 config: measured best)
#define CH    256   // SEQ / NC

#define CHK   64    // LSTM chunk length (2 chunks per thread; r11 config)
#define NGRP  128   // chunk-pair groups per direction (NGRP*2*CHK = SEQ)
#define BURN  32    // burn-in steps (r11-validated)
#define NLKK  30    // kk cached in LDS (144 KB)
#define NSG   15    // streamed groups of 8 kk (120 streamed kk)
#define GSZ   8     // kk per streamed group; 3 buffers x 32 VGPRs = 96
#define XPAD  64    // xg row padding on each side (burn-in over-reads)
#define XROW  (SEQ + 2*XPAD)

__device__ __forceinline__ float rcp_fast(float x){ return __builtin_amdgcn_rcpf(x); }
__device__ __forceinline__ float sigmoidf_(float x){ return rcp_fast(1.f + __expf(-x)); }
__device__ __forceinline__ float tanhf_fast(float x){
    float e = __expf(-2.f * fabsf(x));
    float r = (1.f - e) * rcp_fast(1.f + e);
    return copysignf(r, x);
}

// ---- f16 helpers ----------------------------------------------------------
__device__ __forceinline__ uint16_t f16_bits(float x){
    union { _Float16 h; uint16_t u; } v; v.h = (_Float16)x; return v.u;
}
__device__ __forceinline__ float f16_to_f32(uint16_t u){
    union { _Float16 h; uint16_t u; } v; v.u = u; return (float)v.h;
}
__device__ __forceinline__ uint32_t pack_f16x2(float a, float b){
    return (uint32_t)f16_bits(a) | ((uint32_t)f16_bits(b) << 16);
}
// acc += w.lo*h.lo + w.hi*h.hi  -- single VOP3P dot2
__device__ __forceinline__ float dot2f16(uint32_t w, uint32_t h, float acc){
    float out;
    asm("v_dot2_f32_f16 %0, %1, %2, %3" : "=v"(out) : "v"(w), "v"(h), "v"(acc));
    return out;
}

// ---------------------------------------------------------------------------
// Phase A (fused): blocks [0,1024): xg compute; blocks [1024, 1024+1407):
// w_hh pack; first pack block zero-inits done-counters.
// ---------------------------------------------------------------------------
__global__ __launch_bounds__(256) void xg_prep_kernel(
    const int* __restrict__ sent, const float* __restrict__ embed,
    const float* __restrict__ w_ih_f, const float* __restrict__ b_ih_f, const float* __restrict__ b_hh_f,
    const float* __restrict__ w_ih_b, const float* __restrict__ b_ih_b, const float* __restrict__ b_hh_b,
    const float* __restrict__ w_hh_f, const float* __restrict__ w_hh_b,
    uint16_t* __restrict__ xg, uint32_t* __restrict__ wpk, int* __restrict__ cnt)
{
    if (blockIdx.x >= 1024){
        const int idx = (blockIdx.x - 1024) * 256 + threadIdx.x;
        if (blockIdx.x == 1024 && threadIdx.x == 0){ cnt[0] = 0; cnt[1] = 0; }
        if (idx >= 2 * 150 * 1200) return;
        const int d  = idx / 180000;
        const int rm = idx % 180000;
        const int q  = rm % 1200;      // q = u*4 + gate
        const int u    = q >> 2;
        const int gate = q & 3;
        const int r    = gate * 300 + u;
        const int kk = rm / 1200;
        const float* w = d ? w_hh_b : w_hh_f;
        const float a = w[(size_t)r * HID + 2*kk];
        const float b = w[(size_t)r * HID + 2*kk + 1];
        wpk[idx] = pack_f16x2(a, b);
        return;
    }
    const int tg = blockIdx.x / 16;
    const int rg = blockIdx.x % 16;
    const int d  = rg / 8;
    const int rbase = (rg % 8) * 150;
    const int t = tg * 256 + threadIdx.x;

    __shared__ uint32_t stage[256 * 75];   // 76.8 KB

    const float* w_ih = d ? w_ih_b : w_ih_f;
    const float* b_ih = d ? b_ih_b : b_ih_f;
    const float* b_hh = d ? b_hh_b : b_hh_f;

    const int idx = sent[t];
    float e[EMB];
    const float* ep = embed + (size_t)idx * EMB;
    #pragma unroll
    for (int c = 0; c < EMB; c += 2){
        float2 v = *(const float2*)(ep + c);
        e[c] = v.x; e[c+1] = v.y;
    }
    #pragma unroll 1
    for (int rr = 0; rr < 150; rr += 2){
        float acc[2];
        #pragma unroll
        for (int k = 0; k < 2; k++){
            const int row = rbase + rr + k;
            const float* wr = w_ih + (size_t)row * EMB;
            float a0 = 0.f, a1 = 0.f;
            #pragma unroll
            for (int c = 0; c < EMB; c += 2){
                a0 += e[c]   * wr[c];
                a1 += e[c+1] * wr[c+1];
            }
            acc[k] = a0 + a1 + b_ih[row] + b_hh[row];
        }
        stage[threadIdx.x * 75 + (rr >> 1)] = pack_f16x2(acc[0], acc[1]);
    }
    __syncthreads();
    uint32_t* outb = (uint32_t*)xg + ((size_t)d * XROW + XPAD + (size_t)tg * 256) * 600 + (rbase >> 1);
    #pragma unroll 1
    for (int ee = threadIdx.x; ee < 256 * 75; ee += 256){
        const int tt = ee / 75, cc = ee % 75;
        outb[(size_t)tt * 600 + cc] = stage[ee];
    }
}

// ---------------------------------------------------------------------------
// Phase B: chunk-parallel LSTM (round-20: depth-2 stream via triple buffer).
// 256 blocks, 320 threads, NB=2/CHK=64/BURN=32 (r11 math). The 120 streamed
// kk are 15 groups of 8; buffers A/B/C keep TWO groups (16 KB) in flight at
// all times (r2 evidence: 41 B/cyc achievable; r11's single-group ping-pong
// measured only ~34 B/cyc). Linear group order (r9: order immaterial).
// Cross-step prefetch is 2 groups deep.
// ---------------------------------------------------------------------------
#define LDG(BUF, G)                                                \
    {  const uint4* wgp = wq + (size_t)(NLKK + (G)*GSZ) * 300;     \
       _Pragma("unroll")                                           \
       for (int j = 0; j < GSZ; j++) BUF[j] = wgp[(size_t)j * 300]; }

#define DOTPAIR(W0, W1, H4)                                        \
        a00 = dot2f16((W0).x, (H4).x, a00); a10 = dot2f16((W0).x, (H4).y, a10); \
        a01 = dot2f16((W0).y, (H4).x, a01); a11 = dot2f16((W0).y, (H4).y, a11); \
        a02 = dot2f16((W0).z, (H4).x, a02); a12 = dot2f16((W0).z, (H4).y, a12); \
        a03 = dot2f16((W0).w, (H4).x, a03); a13 = dot2f16((W0).w, (H4).y, a13); \
        a00 = dot2f16((W1).x, (H4).z, a00); a10 = dot2f16((W1).x, (H4).w, a10); \
        a01 = dot2f16((W1).y, (H4).z, a01); a11 = dot2f16((W1).y, (H4).w, a11); \
        a02 = dot2f16((W1).z, (H4).z, a02); a12 = dot2f16((W1).z, (H4).w, a12); \
        a03 = dot2f16((W1).w, (H4).z, a03); a13 = dot2f16((W1).w, (H4).w, a13);

#define CMPG(BUF, G)                                               \
    {  const uint4* hgp = hq4 + (NLKK + (G)*GSZ)/2;                \
       _Pragma("unroll")                                           \
       for (int j = 0; j < GSZ/2; j++){                            \
        const uint4 h4 = hgp[j];                                   \
        DOTPAIR(BUF[2*j], BUF[2*j+1], h4)                          \
       } }

#define CMPGRP_L                                                   \
    _Pragma("unroll")                                              \
    for (int j = 0; j < NLKK/2; j++){                              \
        const uint4 h4 = hq4[j];                                   \
        const uint4 w0 = *(const uint4*)(wlds + ((size_t)(2*j) * 1200 + 4*u));   \
        const uint4 w1 = *(const uint4*)(wlds + ((size_t)(2*j+1) * 1200 + 4*u)); \
        DOTPAIR(w0, w1, h4)                                        \
    }

__global__ __launch_bounds__(320, 1) void lstm_kernel(
    const uint32_t* __restrict__ wpk,
    const float* __restrict__ h0, const float* __restrict__ c0,
    const uint16_t* __restrict__ xg, uint32_t* __restrict__ hout)
{
    const int d  = blockIdx.x >> 7;
    const int g  = blockIdx.x & (NGRP - 1);
    const int cb = 2 * g;                  // first chunk id of the pair
    const int tid = threadIdx.x;
    const int u = tid;
    const bool act = tid < HID;

    __shared__ __align__(16) uint32_t wlds[NLKK * 1200];
    __shared__ __align__(16) uint32_t hb[2][150][2];

    const int pdir = d ? -1 : 1;
    const int seqstart = d ? (SEQ - 1) : 0;
    int p = d ? (cb*CHK + CHK-1 + BURN) : (cb*CHK - BURN);

    const uint32_t* wd  = wpk + (size_t)d * 150 * 1200;
    const uint4*    wq  = ((const uint4*)wd) + u;
    const uint16_t* xgd = xg + ((size_t)d * XROW + XPAD) * G4;

    for (int idx = tid; idx < NLKK * 1200; idx += 320) wlds[idx] = wd[idx];

    float cs0 = 0.f, cs1 = 0.f;
    float h0v = 0.f, c0v = 0.f;
    if (act){ h0v = h0[d*HID + u]; c0v = c0[d*HID + u]; }
    if (tid < 150){ hb[0][tid][0] = 0; hb[0][tid][1] = 0; }
    __syncthreads();

    const uint16_t* xp0 = xgd + (size_t)p * G4 + u;
    const uint16_t* xp1 = xp0 + (size_t)CHK * G4;
    const ptrdiff_t xstep = (ptrdiff_t)pdir * G4;

    uint16_t xa[2][4];
    uint4 A[GSZ], B[GSZ], C[GSZ];
    if (act){
        xa[0][0] = xp0[0]; xa[0][1] = xp0[300]; xa[0][2] = xp0[600]; xa[0][3] = xp0[900];
        xa[1][0] = xp1[0]; xa[1][1] = xp1[300]; xa[1][2] = xp1[600]; xa[1][3] = xp1[900];
        LDG(A, 0)                      // prologue: 2 groups in flight
        LDG(B, 1)
    }
    xp0 += xstep; xp1 += xstep;

    const int nsteps = CHK + BURN;   // 96
    #pragma unroll 1
    for (int i = 0; i < nsteps; i++){
        const int cur = i & 1;
        const int pn  = p + pdir;

        uint16_t xn[2][4];
        if (act){
            xn[0][0] = xp0[0]; xn[0][1] = xp0[300]; xn[0][2] = xp0[600]; xn[0][3] = xp0[900];
            xn[1][0] = xp1[0]; xn[1][1] = xp1[300]; xn[1][2] = xp1[600]; xn[1][3] = xp1[900];
        }
        xp0 += xstep; xp1 += xstep;

        if (act){
            float a00 = f16_to_f32(xa[0][0]);
            float a01 = f16_to_f32(xa[0][1]);
            float a02 = f16_to_f32(xa[0][2]);
            float a03 = f16_to_f32(xa[0][3]);
            float a10 = f16_to_f32(xa[1][0]);
            float a11 = f16_to_f32(xa[1][1]);
            float a12 = f16_to_f32(xa[1][2]);
            float a13 = f16_to_f32(xa[1][3]);

            const uint4* hq4 = (const uint4*)hb[cur];

            CMPGRP_L                       // 240 LDS dot2s hide A/B latency
            // 5 triples cover groups 0..14 in order; 2 groups always in flight.
            // Last triple's A/B loads are the NEXT STEP's groups 0,1.
            #pragma unroll
            for (int tp = 0; tp < 5; tp++){
                const int p0 = 3*tp;
                LDG(C, p0+2)
                CMPG(A, p0)
                LDG(A, (p0+3 < NSG) ? (p0+3) : 0)
                CMPG(B, p0+1)
                LDG(B, (p0+4 < NSG) ? (p0+4) : 1)
                CMPG(C, p0+2)
            }

            const float gi0 = sigmoidf_(a00);
            const float gf0 = sigmoidf_(a01);
            const float gg0 = tanhf_fast(a02);
            const float go0 = sigmoidf_(a03);
            cs0 = gf0 * cs0 + gi0 * gg0;
            uint16_t hw0 = f16_bits(go0 * tanhf_fast(cs0));
            if (pn == seqstart){ cs0 = c0v; hw0 = f16_bits(h0v); }

            const float gi1 = sigmoidf_(a10);
            const float gf1 = sigmoidf_(a11);
            const float gg1 = tanhf_fast(a12);
            const float go1 = sigmoidf_(a13);
            cs1 = gf1 * cs1 + gi1 * gg1;
            uint16_t hw1 = f16_bits(go1 * tanhf_fast(cs1));
            if (pn + CHK == seqstart){ cs1 = c0v; hw1 = f16_bits(h0v); }

            uint16_t* hbn = (uint16_t*)hb[cur ^ 1];
            hbn[(u>>1)*4 + (u&1)]     = hw0;
            hbn[(u>>1)*4 + 2 + (u&1)] = hw1;
        }
        __syncthreads();

        if (i >= BURN && tid < 300){
            const int ci = tid / 150, kk = tid % 150;
            const uint32_t* hn = (const uint32_t*)hb[cur ^ 1];
            hout[((size_t)d * SEQ + (p + ci*CHK)) * 150 + kk] = hn[kk*2 + ci];
        }
        p = pn;
        xa[0][0] = xn[0][0]; xa[0][1] = xn[0][1]; xa[0][2] = xn[0][2]; xa[0][3] = xn[0][3];
        xa[1][0] = xn[1][0]; xa[1][1] = xn[1][1]; xa[1][2] = xn[1][2]; xa[1][3] = xn[1][3];
    }
}

// ---------------------------------------------------------------------------
// Phase C: feats[t][j] = [hf,hb] @ w_tag.T + b_tag. 256 blocks x 256 thr.
// ---------------------------------------------------------------------------
__global__ __launch_bounds__(256) void feats_kernel(
    const uint32_t* __restrict__ hout, const float* __restrict__ w_tag,
    const float* __restrict__ b_tag, float* __restrict__ feats)
{
    const int tl = threadIdx.x & 63;
    const int jg = threadIdx.x >> 6;
    const int t  = blockIdx.x * 64 + tl;
    float acc[5] = {0.f,0.f,0.f,0.f,0.f};
    #pragma unroll 1
    for (int dd = 0; dd < 2; dd++){
        const uint32_t* hp = hout + ((size_t)dd * SEQ + t) * 150;
        #pragma unroll 1
        for (int kw = 0; kw < 150; kw++){
            const uint32_t pk = hp[kw];
            const float hl = f16_to_f32((uint16_t)(pk & 0xffffu));
            const float hh = f16_to_f32((uint16_t)(pk >> 16));
            #pragma unroll
            for (int jj = 0; jj < 5; jj++){
                const float* wrow = w_tag + (size_t)(jg*5 + jj) * 600 + dd*300 + 2*kw;
                acc[jj] += hl * wrow[0] + hh * wrow[1];
            }
        }
    }
    #pragma unroll
    for (int jj = 0; jj < 5; jj++)
        feats[(size_t)t * NTAG + jg*5 + jj] = acc[jj] + b_tag[jg*5 + jj];
}

// ---------------------------------------------------------------------------
// K1 (+fused K2): per-chunk tropical matrix F_c; LAST block runs the
// sequential chunk-scan (k2). 64 blocks x 512 thr.
// ---------------------------------------------------------------------------
__global__ __launch_bounds__(512) void k1_chunkmat(
    const float* __restrict__ feats, const float* __restrict__ trans, float* __restrict__ Fc,
    float* __restrict__ fvb, float* __restrict__ score_out, int* __restrict__ bestbuf,
    int* __restrict__ cnt)
{
    const int c = blockIdx.x;
    const int tid = threadIdx.x;
    __shared__ float fl[CH * NTAG];
    __shared__ float M[2][NTAG * NTAG];
    __shared__ int lastflag;
    for (int i = tid; i < CH*NTAG; i += 512) fl[i] = feats[(size_t)c * CH * NTAG + i];
    const int j = tid / NTAG, p = tid % NTAG;
    float tr[NTAG];
    if (tid < 400){
        #pragma unroll
        for (int q = 0; q < NTAG; q++) tr[q] = trans[j*NTAG + q];
        M[0][tid] = (j == p) ? 0.f : -1e30f;
    }
    __syncthreads();
    #pragma unroll 1
    for (int t = 0; t < CH; t++){
        const int cur = t & 1, nxt = cur ^ 1;
        if (tid < 400){
            float best = -1e38f;
            #pragma unroll
            for (int q = 0; q < NTAG; q++)
                best = fmaxf(best, tr[q] + M[cur][q*NTAG + p]);
            M[nxt][tid] = best + fl[t*NTAG + j];
        }
        __syncthreads();
    }
    if (tid < 400) Fc[(size_t)c * 400 + tid] = M[CH & 1][tid];

    __threadfence();
    __syncthreads();
    if (tid == 0) lastflag = (atomicAdd(&cnt[0], 1) == NC - 1) ? 1 : 0;
    __syncthreads();
    if (!lastflag) return;
    __threadfence();
    if (tid >= 64) return;
    const int jj = tid;
    const bool act = jj < NTAG;
    float fv = (jj == START) ? 0.f : NEGV;
    #pragma unroll 1
    for (int cc = 0; cc < NC; cc++){
        if (act) fvb[cc*NTAG + jj] = fv;
        float best = -1e38f;
        #pragma unroll
        for (int q = 0; q < NTAG; q++){
            const float fq = __shfl(fv, q, 64);
            if (act) best = fmaxf(best, Fc[(size_t)cc*400 + jj*NTAG + q] + fq);
        }
        fv = act ? best : NEGV;
    }
    const float term = act ? (fv + trans[STOPT*NTAG + jj]) : -1e38f;
    float bs = -1e38f; int bi = 0;
    #pragma unroll
    for (int q = 0; q < NTAG; q++){
        const float v = __shfl(term, q, 64);
        if (v > bs){ bs = v; bi = q; }
    }
    if (jj == 0){ score_out[0] = bs; bestbuf[0] = bi; }
}

// ---------------------------------------------------------------------------
// K3 (+fused K4): per-chunk re-walk -> backpointers + chunk map mu; LAST
// block runs the chunk-boundary backtrace (k4).
// ---------------------------------------------------------------------------
__global__ __launch_bounds__(64) void k3_bp(
    const float* __restrict__ feats, const float* __restrict__ trans,
    const float* __restrict__ fvb, uint8_t* __restrict__ bps, int* __restrict__ mu,
    const int* __restrict__ bestbuf, int* __restrict__ tagend, int* __restrict__ cnt)
{
    const int c = blockIdx.x;
    const int j = threadIdx.x;
    const bool act = j < NTAG;
    __shared__ float fl[CH * NTAG];
    __shared__ uint8_t bp[CH * NTAG];
    __shared__ int lastflag;
    for (int i = j; i < CH*NTAG; i += 64) fl[i] = feats[(size_t)c * CH * NTAG + i];
    float tr[NTAG];
    if (act){
        #pragma unroll
        for (int q = 0; q < NTAG; q++) tr[q] = trans[j*NTAG + q];
    }
    float fv = act ? fvb[c*NTAG + j] : NEGV;
    __syncthreads();
    #pragma unroll 1
    for (int t = 0; t < CH; t++){
        float best = -1e38f; int bi = 0;
        #pragma unroll
        for (int q = 0; q < NTAG; q++){
            const float fq = __shfl(fv, q, 64);
            if (act){
                const float v = tr[q] + fq;
                if (v > best){ best = v; bi = q; }   // strict > : first max (argmax semantics)
            }
        }
        if (act) bp[t*NTAG + j] = (uint8_t)bi;
        fv = act ? (best + fl[t*NTAG + j]) : NEGV;
    }
    __syncthreads();
    int m = act ? j : 0;
    #pragma unroll 1
    for (int t = CH-1; t >= 0; t--){
        if (act) m = bp[t*NTAG + m];
    }
    if (act) mu[c*NTAG + j] = m;
    for (int i = j; i < CH*NTAG; i += 64) bps[(size_t)c * CH * NTAG + i] = bp[i];

    __threadfence();
    __syncthreads();
    if (j == 0) lastflag = (atomicAdd(&cnt[1], 1) == NC - 1) ? 1 : 0;
    __syncthreads();
    if (!lastflag) return;
    __threadfence();
    if (j == 0){
        int g = bestbuf[0];
        tagend[NC-1] = g;
        for (int cc = NC-1; cc >= 1; cc--){ g = mu[cc*NTAG + g]; tagend[cc-1] = g; }
    }
}

// K5: per-chunk path fill -> d_out[1..SEQ] as f32 tags.
__global__ __launch_bounds__(64) void k5_path(
    const uint8_t* __restrict__ bps, const int* __restrict__ tagend, float* __restrict__ outpath)
{
    const int c = blockIdx.x;
    const int tid = threadIdx.x;
    __shared__ uint8_t bp[CH * NTAG];
    __shared__ float pl[CH];
    for (int i = tid; i < CH*NTAG; i += 64) bp[i] = bps[(size_t)c * CH * NTAG + i];
    __syncthreads();
    if (tid == 0){
        int g = tagend[c];
        pl[CH-1] = (float)g;
        for (int t = CH-1; t >= 1; t--){ g = bp[t*NTAG + g]; pl[t-1] = (float)g; }
    }
    __syncthreads();
    for (int i = tid; i < CH; i += 64) outpath[(size_t)c * CH + i] = pl[i];
}

// ---------------------------------------------------------------------------
extern "C" void kernel_launch(void* const* d_in, const int* in_sizes, int n_in,
                              void* d_out, int out_size, void* d_ws, size_t ws_size,
                              hipStream_t stream)
{
    const int*   sent    = (const int*)  d_in[0];
    const float* embed   = (const float*)d_in[1];
    const float* w_ih_f  = (const float*)d_in[2];
    const float* w_hh_f  = (const float*)d_in[3];
    const float* b_ih_f  = (const float*)d_in[4];
    const float* b_hh_f  = (const float*)d_in[5];
    const float* w_ih_b  = (const float*)d_in[6];
    const float* w_hh_b  = (const float*)d_in[7];
    const float* b_ih_b  = (const float*)d_in[8];
    const float* b_hh_b  = (const float*)d_in[9];
    const float* h0      = (const float*)d_in[10];
    const float* c0      = (const float*)d_in[11];
    const float* w_tag   = (const float*)d_in[12];
    const float* b_tag   = (const float*)d_in[13];
    const float* trans   = (const float*)d_in[14];
    float* out = (float*)d_out;

    char* ws = (char*)d_ws;
    size_t off = 0;
    auto alloc = [&](size_t bytes)->char*{
        char* p = ws + off; off += (bytes + 255) & ~(size_t)255; return p;
    };
    uint16_t* xg     = (uint16_t*)alloc(2ull * XROW * G4 * 2);    // 79.2 MB (padded)
    uint32_t* hout   = (uint32_t*)alloc(2ull * SEQ * 150 * 4);    // 19.7 MB
    float*    feats  = (float*)   alloc((size_t)SEQ * NTAG * 4);  // 1.3 MB
    uint32_t* wpk    = (uint32_t*)alloc(2ull * 150 * 1200 * 4);   // 1.44 MB
    float*    Fc     = (float*)   alloc((size_t)NC * 400 * 4);
    float*    fvb    = (float*)   alloc((size_t)NC * NTAG * 4);
    uint8_t*  bps    = (uint8_t*) alloc((size_t)SEQ * NTAG);
    int*      mu     = (int*)     alloc((size_t)NC * NTAG * 4);
    int*      tagend = (int*)     alloc((size_t)NC * 4);
    int*      bestbuf= (int*)     alloc(256);
    int*      cnt    = (int*)     alloc(256);

    const int prep_blocks = (2*150*1200 + 255)/256;
    hipLaunchKernelGGL(xg_prep_kernel, dim3(1024 + prep_blocks), dim3(256), 0, stream,
                       sent, embed, w_ih_f, b_ih_f, b_hh_f, w_ih_b, b_ih_b, b_hh_b,
                       w_hh_f, w_hh_b, xg, wpk, cnt);
    hipLaunchKernelGGL(lstm_kernel, dim3(2 * NGRP), dim3(320), 0, stream,
                       wpk, h0, c0, xg, hout);
    hipLaunchKernelGGL(feats_kernel, dim3(256), dim3(256), 0, stream,
                       hout, w_tag, b_tag, feats);
    hipLaunchKernelGGL(k1_chunkmat, dim3(NC), dim3(512), 0, stream,
                       feats, trans, Fc, fvb, out, bestbuf, cnt);
    hipLaunchKernelGGL(k3_bp, dim3(NC), dim3(64), 0, stream,
                       feats, trans, fvb, bps, mu, bestbuf, tagend, cnt);
    hipLaunchKernelGGL(k5_path, dim3(NC), dim3(64), 0, stream, bps, tagend, out + 1);
}

// Round 16
// 1421.620 us; speedup vs baseline: 2.9913x; 2.9913x over previous
//
#include <hip/hip_runtime.h>
#include <stdint.h>

#define SEQ   16384
#define EMB   50
#define HID   300
#define G4    1200
#define NTAG  20
#define START 18
#define STOPT 19
#define NEGV  -10000.0f
#define NC    64    // viterbi chunks (r8 config: measured best)
#define CH    256   // SEQ / NC

#define CHK   64    // LSTM chunk length (2 chunks per thread; r11 config)
#define NGRP  128   // chunk-pair groups per direction (NGRP*2*CHK = SEQ)
#define BURN  32    // burn-in steps (r11-validated)
#define NLKK  30    // kk cached in LDS (144 KB)
#define NSG   12    // streamed groups of 10 kk
#define XPAD  64    // xg row padding on each side (burn-in over-reads)
#define XROW  (SEQ + 2*XPAD)

__device__ __forceinline__ float rcp_fast(float x){ return __builtin_amdgcn_rcpf(x); }
__device__ __forceinline__ float sigmoidf_(float x){ return rcp_fast(1.f + __expf(-x)); }
__device__ __forceinline__ float tanhf_fast(float x){
    float e = __expf(-2.f * fabsf(x));
    float r = (1.f - e) * rcp_fast(1.f + e);
    return copysignf(r, x);
}

// ---- f16 helpers ----------------------------------------------------------
__device__ __forceinline__ uint16_t f16_bits(float x){
    union { _Float16 h; uint16_t u; } v; v.h = (_Float16)x; return v.u;
}
__device__ __forceinline__ float f16_to_f32(uint16_t u){
    union { _Float16 h; uint16_t u; } v; v.u = u; return (float)v.h;
}
__device__ __forceinline__ uint32_t pack_f16x2(float a, float b){
    return (uint32_t)f16_bits(a) | ((uint32_t)f16_bits(b) << 16);
}
// acc += w.lo*h.lo + w.hi*h.hi  -- single VOP3P dot2
__device__ __forceinline__ float dot2f16(uint32_t w, uint32_t h, float acc){
    float out;
    asm("v_dot2_f32_f16 %0, %1, %2, %3" : "=v"(out) : "v"(w), "v"(h), "v"(acc));
    return out;
}

// ---------------------------------------------------------------------------
// Phase A (fused): blocks [0,1024): xg compute; blocks [1024, 1024+1407):
// w_hh pack; the very first pack block also zero-inits the done-counters.
// xg rows padded by XPAD so burn-in over-reads are in-bounds.
// ---------------------------------------------------------------------------
__global__ __launch_bounds__(256) void xg_prep_kernel(
    const int* __restrict__ sent, const float* __restrict__ embed,
    const float* __restrict__ w_ih_f, const float* __restrict__ b_ih_f, const float* __restrict__ b_hh_f,
    const float* __restrict__ w_ih_b, const float* __restrict__ b_ih_b, const float* __restrict__ b_hh_b,
    const float* __restrict__ w_hh_f, const float* __restrict__ w_hh_b,
    uint16_t* __restrict__ xg, uint32_t* __restrict__ wpk, int* __restrict__ cnt)
{
    if (blockIdx.x >= 1024){
        // ---- prep_w part ----
        const int idx = (blockIdx.x - 1024) * 256 + threadIdx.x;
        if (blockIdx.x == 1024 && threadIdx.x == 0){ cnt[0] = 0; cnt[1] = 0; }
        if (idx >= 2 * 150 * 1200) return;
        const int d  = idx / 180000;
        const int rm = idx % 180000;
        const int q  = rm % 1200;      // q = u*4 + gate
        const int u    = q >> 2;
        const int gate = q & 3;
        const int r    = gate * 300 + u;
        const int kk = rm / 1200;
        const float* w = d ? w_hh_b : w_hh_f;
        const float a = w[(size_t)r * HID + 2*kk];
        const float b = w[(size_t)r * HID + 2*kk + 1];
        wpk[idx] = pack_f16x2(a, b);
        return;
    }
    // ---- xg part ----
    const int tg = blockIdx.x / 16;
    const int rg = blockIdx.x % 16;
    const int d  = rg / 8;
    const int rbase = (rg % 8) * 150;
    const int t = tg * 256 + threadIdx.x;

    __shared__ uint32_t stage[256 * 75];   // 256 t x 150 f16 = 76.8 KB

    const float* w_ih = d ? w_ih_b : w_ih_f;
    const float* b_ih = d ? b_ih_b : b_ih_f;
    const float* b_hh = d ? b_hh_b : b_hh_f;

    const int idx = sent[t];
    float e[EMB];
    const float* ep = embed + (size_t)idx * EMB;
    #pragma unroll
    for (int c = 0; c < EMB; c += 2){
        float2 v = *(const float2*)(ep + c);
        e[c] = v.x; e[c+1] = v.y;
    }
    #pragma unroll 1
    for (int rr = 0; rr < 150; rr += 2){
        float acc[2];
        #pragma unroll
        for (int k = 0; k < 2; k++){
            const int row = rbase + rr + k;
            const float* wr = w_ih + (size_t)row * EMB;
            float a0 = 0.f, a1 = 0.f;
            #pragma unroll
            for (int c = 0; c < EMB; c += 2){
                a0 += e[c]   * wr[c];
                a1 += e[c+1] * wr[c+1];
            }
            acc[k] = a0 + a1 + b_ih[row] + b_hh[row];
        }
        stage[threadIdx.x * 75 + (rr >> 1)] = pack_f16x2(acc[0], acc[1]);
    }
    __syncthreads();
    uint32_t* outb = (uint32_t*)xg + ((size_t)d * XROW + XPAD + (size_t)tg * 256) * 600 + (rbase >> 1);
    #pragma unroll 1
    for (int ee = threadIdx.x; ee < 256 * 75; ee += 256){
        const int tt = ee / 75, cc = ee % 75;
        outb[(size_t)tt * 600 + cc] = stage[ee];
    }
}

// ---------------------------------------------------------------------------
// Phase B: chunk-parallel LSTM (r11 structure verbatim: NB=2 in-thread,
// CHK=64, BURN=32, uint4 A/B ping-pong, LDS cache 30 kk).
// ---------------------------------------------------------------------------
#define LDGRPR(BUF, GR)                                            \
    {  const uint4* wgp = wq + (size_t)(NLKK + (GR)*10) * 300;     \
       _Pragma("unroll")                                           \
       for (int j = 0; j < 10; j++) BUF[j] = wgp[(size_t)j * 300]; }

#define CMPGRPR(BUF, GR)                                           \
    {  const uint4* hgp = hq4 + (NLKK/2) + (GR)*5;                 \
       _Pragma("unroll")                                           \
       for (int j = 0; j < 5; j++){                                \
        const uint4 h4 = hgp[j];                                   \
        const uint4 w0 = BUF[2*j];                                 \
        const uint4 w1 = BUF[2*j+1];                               \
        a00 = dot2f16(w0.x, h4.x, a00); a10 = dot2f16(w0.x, h4.y, a10); \
        a01 = dot2f16(w0.y, h4.x, a01); a11 = dot2f16(w0.y, h4.y, a11); \
        a02 = dot2f16(w0.z, h4.x, a02); a12 = dot2f16(w0.z, h4.y, a12); \
        a03 = dot2f16(w0.w, h4.x, a03); a13 = dot2f16(w0.w, h4.y, a13); \
        a00 = dot2f16(w1.x, h4.z, a00); a10 = dot2f16(w1.x, h4.w, a10); \
        a01 = dot2f16(w1.y, h4.z, a01); a11 = dot2f16(w1.y, h4.w, a11); \
        a02 = dot2f16(w1.z, h4.z, a02); a12 = dot2f16(w1.z, h4.w, a12); \
        a03 = dot2f16(w1.w, h4.z, a03); a13 = dot2f16(w1.w, h4.w, a13); \
       } }

#define CMPGRP_L                                                   \
    _Pragma("unroll")                                              \
    for (int j = 0; j < NLKK/2; j++){                              \
        const uint4 h4 = hq4[j];                                   \
        const uint4 w0 = *(const uint4*)(wlds + ((size_t)(2*j) * 1200 + 4*u));   \
        const uint4 w1 = *(const uint4*)(wlds + ((size_t)(2*j+1) * 1200 + 4*u)); \
        a00 = dot2f16(w0.x, h4.x, a00); a10 = dot2f16(w0.x, h4.y, a10); \
        a01 = dot2f16(w0.y, h4.x, a01); a11 = dot2f16(w0.y, h4.y, a11); \
        a02 = dot2f16(w0.z, h4.x, a02); a12 = dot2f16(w0.z, h4.y, a12); \
        a03 = dot2f16(w0.w, h4.x, a03); a13 = dot2f16(w0.w, h4.y, a13); \
        a00 = dot2f16(w1.x, h4.z, a00); a10 = dot2f16(w1.x, h4.w, a10); \
        a01 = dot2f16(w1.y, h4.z, a01); a11 = dot2f16(w1.y, h4.w, a11); \
        a02 = dot2f16(w1.z, h4.z, a02); a12 = dot2f16(w1.z, h4.w, a12); \
        a03 = dot2f16(w1.w, h4.z, a03); a13 = dot2f16(w1.w, h4.w, a13); \
    }

__global__ __launch_bounds__(320, 1) void lstm_kernel(
    const uint32_t* __restrict__ wpk,
    const float* __restrict__ h0, const float* __restrict__ c0,
    const uint16_t* __restrict__ xg, uint32_t* __restrict__ hout)
{
    const int d  = blockIdx.x >> 7;
    const int g  = blockIdx.x & (NGRP - 1);
    const int cb = 2 * g;                  // first chunk id of the pair
    const int tid = threadIdx.x;
    const int u = tid;
    const bool act = tid < HID;
    const int gstart = blockIdx.x % NSG;   // per-block stream rotation

    __shared__ __align__(16) uint32_t wlds[NLKK * 1200];
    __shared__ __align__(16) uint32_t hb[2][150][2];

    const int pdir = d ? -1 : 1;
    const int seqstart = d ? (SEQ - 1) : 0;
    int p = d ? (cb*CHK + CHK-1 + BURN) : (cb*CHK - BURN);

    const uint32_t* wd  = wpk + (size_t)d * 150 * 1200;
    const uint4*    wq  = ((const uint4*)wd) + u;
    const uint16_t* xgd = xg + ((size_t)d * XROW + XPAD) * G4;

    for (int idx = tid; idx < NLKK * 1200; idx += 320) wlds[idx] = wd[idx];

    float cs0 = 0.f, cs1 = 0.f;
    float h0v = 0.f, c0v = 0.f;
    if (act){ h0v = h0[d*HID + u]; c0v = c0[d*HID + u]; }
    if (tid < 150){ hb[0][tid][0] = 0; hb[0][tid][1] = 0; }
    __syncthreads();

    const uint16_t* xp0 = xgd + (size_t)p * G4 + u;
    const uint16_t* xp1 = xp0 + (size_t)CHK * G4;
    const ptrdiff_t xstep = (ptrdiff_t)pdir * G4;

    uint16_t xa[2][4];
    uint4 A[10], B[10];
    if (act){
        xa[0][0] = xp0[0]; xa[0][1] = xp0[300]; xa[0][2] = xp0[600]; xa[0][3] = xp0[900];
        xa[1][0] = xp1[0]; xa[1][1] = xp1[300]; xa[1][2] = xp1[600]; xa[1][3] = xp1[900];
        LDGRPR(A, gstart)                 // prologue prefetch of first group
    }
    xp0 += xstep; xp1 += xstep;

    const int nsteps = CHK + BURN;   // 96
    #pragma unroll 1
    for (int i = 0; i < nsteps; i++){
        const int cur = i & 1;
        const int pn  = p + pdir;

        uint16_t xn[2][4];
        if (act){
            xn[0][0] = xp0[0]; xn[0][1] = xp0[300]; xn[0][2] = xp0[600]; xn[0][3] = xp0[900];
            xn[1][0] = xp1[0]; xn[1][1] = xp1[300]; xn[1][2] = xp1[600]; xn[1][3] = xp1[900];
        }
        xp0 += xstep; xp1 += xstep;

        if (act){
            float a00 = f16_to_f32(xa[0][0]);
            float a01 = f16_to_f32(xa[0][1]);
            float a02 = f16_to_f32(xa[0][2]);
            float a03 = f16_to_f32(xa[0][3]);
            float a10 = f16_to_f32(xa[1][0]);
            float a11 = f16_to_f32(xa[1][1]);
            float a12 = f16_to_f32(xa[1][2]);
            float a13 = f16_to_f32(xa[1][3]);

            const uint4* hq4 = (const uint4*)hb[cur];

            CMPGRP_L                       // 240 LDS dot2s hide A's latency
            int gc = gstart;               // group currently in A
            #pragma unroll 1
            for (int pp = 0; pp < 5; pp++){
                int g1 = gc + 1; if (g1 >= NSG) g1 -= NSG;
                int g2 = g1 + 1; if (g2 >= NSG) g2 -= NSG;
                LDGRPR(B, g1)
                CMPGRPR(A, gc)
                LDGRPR(A, g2)
                CMPGRPR(B, g1)
                gc = g2;
            }
            int g1 = gc + 1; if (g1 >= NSG) g1 -= NSG;
            LDGRPR(B, g1)
            CMPGRPR(A, gc)
            LDGRPR(A, gstart)              // cross-step prefetch (h-independent)
            CMPGRPR(B, g1)

            const float gi0 = sigmoidf_(a00);
            const float gf0 = sigmoidf_(a01);
            const float gg0 = tanhf_fast(a02);
            const float go0 = sigmoidf_(a03);
            cs0 = gf0 * cs0 + gi0 * gg0;
            uint16_t hw0 = f16_bits(go0 * tanhf_fast(cs0));
            if (pn == seqstart){ cs0 = c0v; hw0 = f16_bits(h0v); }

            const float gi1 = sigmoidf_(a10);
            const float gf1 = sigmoidf_(a11);
            const float gg1 = tanhf_fast(a12);
            const float go1 = sigmoidf_(a13);
            cs1 = gf1 * cs1 + gi1 * gg1;
            uint16_t hw1 = f16_bits(go1 * tanhf_fast(cs1));
            if (pn + CHK == seqstart){ cs1 = c0v; hw1 = f16_bits(h0v); }

            uint16_t* hbn = (uint16_t*)hb[cur ^ 1];
            hbn[(u>>1)*4 + (u&1)]     = hw0;
            hbn[(u>>1)*4 + 2 + (u&1)] = hw1;
        }
        __syncthreads();

        if (i >= BURN && tid < 300){
            const int ci = tid / 150, kk = tid % 150;
            const uint32_t* hn = (const uint32_t*)hb[cur ^ 1];
            hout[((size_t)d * SEQ + (p + ci*CHK)) * 150 + kk] = hn[kk*2 + ci];
        }
        p = pn;
        xa[0][0] = xn[0][0]; xa[0][1] = xn[0][1]; xa[0][2] = xn[0][2]; xa[0][3] = xn[0][3];
        xa[1][0] = xn[1][0]; xa[1][1] = xn[1][1]; xa[1][2] = xn[1][2]; xa[1][3] = xn[1][3];
    }
}

// ---------------------------------------------------------------------------
// Phase C: feats[t][j] = [hf,hb] @ w_tag.T + b_tag. 256 blocks x 256 thr.
// ---------------------------------------------------------------------------
__global__ __launch_bounds__(256) void feats_kernel(
    const uint32_t* __restrict__ hout, const float* __restrict__ w_tag,
    const float* __restrict__ b_tag, float* __restrict__ feats)
{
    const int tl = threadIdx.x & 63;
    const int jg = threadIdx.x >> 6;
    const int t  = blockIdx.x * 64 + tl;
    float acc[5] = {0.f,0.f,0.f,0.f,0.f};
    #pragma unroll 1
    for (int dd = 0; dd < 2; dd++){
        const uint32_t* hp = hout + ((size_t)dd * SEQ + t) * 150;
        #pragma unroll 1
        for (int kw = 0; kw < 150; kw++){
            const uint32_t pk = hp[kw];
            const float hl = f16_to_f32((uint16_t)(pk & 0xffffu));
            const float hh = f16_to_f32((uint16_t)(pk >> 16));
            #pragma unroll
            for (int jj = 0; jj < 5; jj++){
                const float* wrow = w_tag + (size_t)(jg*5 + jj) * 600 + dd*300 + 2*kw;
                acc[jj] += hl * wrow[0] + hh * wrow[1];
            }
        }
    }
    #pragma unroll
    for (int jj = 0; jj < 5; jj++)
        feats[(size_t)t * NTAG + jg*5 + jj] = acc[jj] + b_tag[jg*5 + jj];
}

// ---------------------------------------------------------------------------
// K1 (+fused K2): per-chunk tropical matrix F_c; the LAST block to finish
// additionally runs the sequential chunk-scan (k2) producing fvb, score,
// best tag. 64 blocks x 512 thr.
// ---------------------------------------------------------------------------
__global__ __launch_bounds__(512) void k1_chunkmat(
    const float* __restrict__ feats, const float* __restrict__ trans, float* __restrict__ Fc,
    float* __restrict__ fvb, float* __restrict__ score_out, int* __restrict__ bestbuf,
    int* __restrict__ cnt)
{
    const int c = blockIdx.x;
    const int tid = threadIdx.x;
    __shared__ float fl[CH * NTAG];
    __shared__ float M[2][NTAG * NTAG];
    __shared__ int lastflag;
    for (int i = tid; i < CH*NTAG; i += 512) fl[i] = feats[(size_t)c * CH * NTAG + i];
    const int j = tid / NTAG, p = tid % NTAG;
    float tr[NTAG];
    if (tid < 400){
        #pragma unroll
        for (int q = 0; q < NTAG; q++) tr[q] = trans[j*NTAG + q];
        M[0][tid] = (j == p) ? 0.f : -1e30f;
    }
    __syncthreads();
    #pragma unroll 1
    for (int t = 0; t < CH; t++){
        const int cur = t & 1, nxt = cur ^ 1;
        if (tid < 400){
            float best = -1e38f;
            #pragma unroll
            for (int q = 0; q < NTAG; q++)
                best = fmaxf(best, tr[q] + M[cur][q*NTAG + p]);
            M[nxt][tid] = best + fl[t*NTAG + j];
        }
        __syncthreads();
    }
    if (tid < 400) Fc[(size_t)c * 400 + tid] = M[CH & 1][tid];

    // ---- last-block k2 ----
    __threadfence();
    __syncthreads();
    if (tid == 0) lastflag = (atomicAdd(&cnt[0], 1) == NC - 1) ? 1 : 0;
    __syncthreads();
    if (!lastflag) return;
    __threadfence();
    if (tid >= 64) return;
    const int jj = tid;
    const bool act = jj < NTAG;
    float fv = (jj == START) ? 0.f : NEGV;
    #pragma unroll 1
    for (int cc = 0; cc < NC; cc++){
        if (act) fvb[cc*NTAG + jj] = fv;
        float best = -1e38f;
        #pragma unroll
        for (int q = 0; q < NTAG; q++){
            const float fq = __shfl(fv, q, 64);
            if (act) best = fmaxf(best, Fc[(size_t)cc*400 + jj*NTAG + q] + fq);
        }
        fv = act ? best : NEGV;
    }
    const float term = act ? (fv + trans[STOPT*NTAG + jj]) : -1e38f;
    float bs = -1e38f; int bi = 0;
    #pragma unroll
    for (int q = 0; q < NTAG; q++){
        const float v = __shfl(term, q, 64);
        if (v > bs){ bs = v; bi = q; }
    }
    if (jj == 0){ score_out[0] = bs; bestbuf[0] = bi; }
}

// ---------------------------------------------------------------------------
// K3 (+fused K4): per-chunk re-walk -> backpointers + chunk map mu; LAST
// block also runs the sequential chunk-boundary backtrace (k4) -> tagend.
// ---------------------------------------------------------------------------
__global__ __launch_bounds__(64) void k3_bp(
    const float* __restrict__ feats, const float* __restrict__ trans,
    const float* __restrict__ fvb, uint8_t* __restrict__ bps, int* __restrict__ mu,
    const int* __restrict__ bestbuf, int* __restrict__ tagend, int* __restrict__ cnt)
{
    const int c = blockIdx.x;
    const int j = threadIdx.x;
    const bool act = j < NTAG;
    __shared__ float fl[CH * NTAG];
    __shared__ uint8_t bp[CH * NTAG];
    __shared__ int lastflag;
    for (int i = j; i < CH*NTAG; i += 64) fl[i] = feats[(size_t)c * CH * NTAG + i];
    float tr[NTAG];
    if (act){
        #pragma unroll
        for (int q = 0; q < NTAG; q++) tr[q] = trans[j*NTAG + q];
    }
    float fv = act ? fvb[c*NTAG + j] : NEGV;
    __syncthreads();
    #pragma unroll 1
    for (int t = 0; t < CH; t++){
        float best = -1e38f; int bi = 0;
        #pragma unroll
        for (int q = 0; q < NTAG; q++){
            const float fq = __shfl(fv, q, 64);
            if (act){
                const float v = tr[q] + fq;
                if (v > best){ best = v; bi = q; }   // strict > : first max (argmax semantics)
            }
        }
        if (act) bp[t*NTAG + j] = (uint8_t)bi;
        fv = act ? (best + fl[t*NTAG + j]) : NEGV;
    }
    __syncthreads();
    int m = act ? j : 0;
    #pragma unroll 1
    for (int t = CH-1; t >= 0; t--){
        if (act) m = bp[t*NTAG + m];
    }
    if (act) mu[c*NTAG + j] = m;
    for (int i = j; i < CH*NTAG; i += 64) bps[(size_t)c * CH * NTAG + i] = bp[i];

    // ---- last-block k4 ----
    __threadfence();
    __syncthreads();
    if (j == 0) lastflag = (atomicAdd(&cnt[1], 1) == NC - 1) ? 1 : 0;
    __syncthreads();
    if (!lastflag) return;
    __threadfence();
    if (j == 0){
        int g = bestbuf[0];
        tagend[NC-1] = g;
        for (int cc = NC-1; cc >= 1; cc--){ g = mu[cc*NTAG + g]; tagend[cc-1] = g; }
    }
}

// K5: per-chunk path fill -> d_out[1..SEQ] as f32 tags.
__global__ __launch_bounds__(64) void k5_path(
    const uint8_t* __restrict__ bps, const int* __restrict__ tagend, float* __restrict__ outpath)
{
    const int c = blockIdx.x;
    const int tid = threadIdx.x;
    __shared__ uint8_t bp[CH * NTAG];
    __shared__ float pl[CH];
    for (int i = tid; i < CH*NTAG; i += 64) bp[i] = bps[(size_t)c * CH * NTAG + i];
    __syncthreads();
    if (tid == 0){
        int g = tagend[c];
        pl[CH-1] = (float)g;
        for (int t = CH-1; t >= 1; t--){ g = bp[t*NTAG + g]; pl[t-1] = (float)g; }
    }
    __syncthreads();
    for (int i = tid; i < CH; i += 64) outpath[(size_t)c * CH + i] = pl[i];
}

// ---------------------------------------------------------------------------
extern "C" void kernel_launch(void* const* d_in, const int* in_sizes, int n_in,
                              void* d_out, int out_size, void* d_ws, size_t ws_size,
                              hipStream_t stream)
{
    const int*   sent    = (const int*)  d_in[0];
    const float* embed   = (const float*)d_in[1];
    const float* w_ih_f  = (const float*)d_in[2];
    const float* w_hh_f  = (const float*)d_in[3];
    const float* b_ih_f  = (const float*)d_in[4];
    const float* b_hh_f  = (const float*)d_in[5];
    const float* w_ih_b  = (const float*)d_in[6];
    const float* w_hh_b  = (const float*)d_in[7];
    const float* b_ih_b  = (const float*)d_in[8];
    const float* b_hh_b  = (const float*)d_in[9];
    const float* h0      = (const float*)d_in[10];
    const float* c0      = (const float*)d_in[11];
    const float* w_tag   = (const float*)d_in[12];
    const float* b_tag   = (const float*)d_in[13];
    const float* trans   = (const float*)d_in[14];
    float* out = (float*)d_out;

    char* ws = (char*)d_ws;
    size_t off = 0;
    auto alloc = [&](size_t bytes)->char*{
        char* p = ws + off; off += (bytes + 255) & ~(size_t)255; return p;
    };
    uint16_t* xg     = (uint16_t*)alloc(2ull * XROW * G4 * 2);    // 79.2 MB (padded)
    uint32_t* hout   = (uint32_t*)alloc(2ull * SEQ * 150 * 4);    // 19.7 MB
    float*    feats  = (float*)   alloc((size_t)SEQ * NTAG * 4);  // 1.3 MB
    uint32_t* wpk    = (uint32_t*)alloc(2ull * 150 * 1200 * 4);   // 1.44 MB
    float*    Fc     = (float*)   alloc((size_t)NC * 400 * 4);
    float*    fvb    = (float*)   alloc((size_t)NC * NTAG * 4);
    uint8_t*  bps    = (uint8_t*) alloc((size_t)SEQ * NTAG);
    int*      mu     = (int*)     alloc((size_t)NC * NTAG * 4);
    int*      tagend = (int*)     alloc((size_t)NC * 4);
    int*      bestbuf= (int*)     alloc(256);
    int*      cnt    = (int*)     alloc(256);

    const int prep_blocks = (2*150*1200 + 255)/256;
    hipLaunchKernelGGL(xg_prep_kernel, dim3(1024 + prep_blocks), dim3(256), 0, stream,
                       sent, embed, w_ih_f, b_ih_f, b_hh_f, w_ih_b, b_ih_b, b_hh_b,
                       w_hh_f, w_hh_b, xg, wpk, cnt);
    hipLaunchKernelGGL(lstm_kernel, dim3(2 * NGRP), dim3(320), 0, stream,
                       wpk, h0, c0, xg, hout);
    hipLaunchKernelGGL(feats_kernel, dim3(256), dim3(256), 0, stream,
                       hout, w_tag, b_tag, feats);
    hipLaunchKernelGGL(k1_chunkmat, dim3(NC), dim3(512), 0, stream,
                       feats, trans, Fc, fvb, out, bestbuf, cnt);
    hipLaunchKernelGGL(k3_bp, dim3(NC), dim3(64), 0, stream,
                       feats, trans, fvb, bps, mu, bestbuf, tagend, cnt);
    hipLaunchKernelGGL(k5_path, dim3(NC), dim3(64), 0, stream, bps, tagend, out + 1);
}